// Round 4
// baseline (1516.714 us; speedup 1.0000x reference)
//
#include <hip/hip_runtime.h>
#include <hip/hip_bf16.h>

#define CDIM 384
#define NQKV 1152
#define HEADS 12
#define SHIFT_ 4
#define SCALE_Q 0.17677669529663687f  // 32^-0.5

typedef __attribute__((ext_vector_type(8))) short bf16x8;
typedef __attribute__((ext_vector_type(4))) float f32x4;
typedef __attribute__((ext_vector_type(4))) float float4_t;

__device__ inline short f2bf(float f) {
    union { float f; unsigned u; } v; v.f = f;
    unsigned r = v.u + 0x7FFFu + ((v.u >> 16) & 1u);
    return (short)(r >> 16);
}

__device__ inline void gl16(const short* g, const short* l) {
    __builtin_amdgcn_global_load_lds((const __attribute__((address_space(1))) void*)g,
                                     (__attribute__((address_space(3))) void*)l, 16, 0, 0);
}

// inverse of the LDS chunk swizzle (16B chunks, rows of 4 chunks)
__device__ inline int invswz(int c) {
    int b2 = (c >> 2) & 1, b3 = (c >> 3) & 1, b4 = (c >> 4) & 1;
    return (c & ~7) | ((b2 ^ b4) << 2) | (((((c >> 1) & 1)) ^ b3) << 1) | ((c & 1) ^ b2 ^ b4);
}

// ---------------- prep: weight transpose->bf16, bias matrix ----------------
__global__ void prep_kernel(const float* __restrict__ qkv_w,
                            const float* __restrict__ proj_w,
                            const float* __restrict__ bias_table,
                            const int* __restrict__ rel_index,
                            short* __restrict__ qkvwt,
                            short* __restrict__ projwt,
                            float* __restrict__ biasmat) {
    int t = blockIdx.x * 256 + threadIdx.x;
    if (t < NQKV * CDIM) {             // qkvwt[n][k] = qkv_w[k][n]
        int n = t / CDIM, k = t - n * CDIM;
        qkvwt[t] = f2bf(qkv_w[k * NQKV + n]);
    }
    if (t < CDIM * CDIM) {             // projwt[n][k] = proj_w[k][n]
        int n = t / CDIM, k = t - n * CDIM;
        projwt[t] = f2bf(proj_w[k * CDIM + n]);
    }
    if (t < HEADS * 64 * 64) {         // biasmat[h][i][j]
        int h = t >> 12, ij = t & 4095;
        biasmat[t] = bias_table[rel_index[ij] * HEADS + h];
    }
}

// ---------------- fused qkv + attention: one block per window --------------
// 4 waves, wave = 3 heads. All scratch wave-private -> no main-loop barriers.
// Per-wave LDS 14848 B: Q[64][40]s @0 | K[64][40]s @5120 | Vt[32][72]s @10240
//                       P[64][72]s overlays Q+K ; obuf[64][36]s overlays Vt
// Total LDS 4*14848 + 256 = 59648 B  -> 2 blocks/CU (2 waves/SIMD).
__global__ __launch_bounds__(256, 2) void fused_qa(
    const float* __restrict__ x, const short* __restrict__ qkvwt,
    const float* __restrict__ qkv_b, const float* __restrict__ biasmat,
    short* __restrict__ attno)
{
    __shared__ __attribute__((aligned(16))) char smem[59392];
    __shared__ int regbuf[64];
    int tid = threadIdx.x;
    int lane = tid & 63, wv = tid >> 6;
    int lrow = lane & 15, lhi = lane >> 4;
    char* pw  = smem + wv * 14848;
    char* qs  = pw;                    // Q, stride 40 shorts
    char* kst = pw + 5120;             // K, stride 40 shorts
    char* vt  = pw + 10240;            // Vt, stride 72 shorts
    char* pb  = pw;                    // P, stride 72 shorts (overlays Q+K)
    char* ob  = pw + 10240;            // obuf, stride 36 shorts (overlays Vt)

    int w = blockIdx.x;
    int b = w >> 6, wIdx = w & 63;

    if (tid < 64) {                    // shift-mask region ids
        int gh = ((wIdx >> 3) << 3) + (tid >> 3);
        int gw = (wIdx & 7) * 8 + (tid & 7);
        int rh = gh < 56 ? 0 : (gh < 60 ? 1 : 2);
        int rw = gw < 56 ? 0 : (gw < 60 ? 1 : 2);
        regbuf[tid] = rh * 3 + rw;
    }
    __syncthreads();

    // per-lane shifted x row pointers for the 4 row-tiles (A-frag rows)
    const float* rowptr[4];
    #pragma unroll
    for (int rt = 0; rt < 4; rt++) {
        int token = rt * 16 + lrow;
        int gh = ((wIdx >> 3) << 3) + (token >> 3);
        int gw = (wIdx & 7) * 8 + (token & 7);
        int sh_ = (gh + SHIFT_) & 63, sw_ = (gw + SHIFT_) & 63;
        rowptr[rt] = x + (size_t)(b * 4096 + sh_ * 64 + sw_) * CDIM + lhi * 8;
    }

    f32x4 zero = {0.f, 0.f, 0.f, 0.f};
    int regj[4], regi_[4][4];
    #pragma unroll
    for (int tj = 0; tj < 4; tj++) regj[tj] = regbuf[tj * 16 + lrow];
    #pragma unroll
    for (int ti = 0; ti < 4; ti++)
        #pragma unroll
        for (int r = 0; r < 4; r++) regi_[ti][r] = regbuf[ti * 16 + lhi * 4 + r];

    for (int hi = 0; hi < 3; hi++) {
        int h = wv * 3 + hi;
        // ---- qkv GEMM for this head: 64 tok x (32q|32k|32v), K=384 ----
        f32x4 acc[4][6];
        #pragma unroll
        for (int i = 0; i < 4; i++)
            #pragma unroll
            for (int j = 0; j < 6; j++) acc[i][j] = zero;
        const short* brow[6];
        #pragma unroll
        for (int ct = 0; ct < 6; ct++) {
            int part = ct >> 1, sub = ct & 1;
            brow[ct] = qkvwt + (size_t)(part * CDIM + h * 32 + sub * 16 + lrow) * CDIM + lhi * 8;
        }
        #pragma unroll
        for (int ks = 0; ks < 12; ks++) {
            bf16x8 bf[6];
            #pragma unroll
            for (int ct = 0; ct < 6; ct++) bf[ct] = *(const bf16x8*)(brow[ct] + ks * 32);
            bf16x8 af[4];
            #pragma unroll
            for (int rt = 0; rt < 4; rt++) {
                float4_t a0 = *(const float4_t*)(rowptr[rt] + ks * 32);
                float4_t a1 = *(const float4_t*)(rowptr[rt] + ks * 32 + 4);
                #pragma unroll
                for (int i = 0; i < 4; i++) {
                    af[rt][i] = f2bf(a0[i]); af[rt][4 + i] = f2bf(a1[i]);
                }
            }
            __builtin_amdgcn_s_setprio(1);
            #pragma unroll
            for (int rt = 0; rt < 4; rt++)
                #pragma unroll
                for (int ct = 0; ct < 6; ct++)
                    acc[rt][ct] = __builtin_amdgcn_mfma_f32_16x16x32_bf16(af[rt], bf[ct], acc[rt][ct], 0, 0, 0);
            __builtin_amdgcn_s_setprio(0);
        }
        // ---- epilogue: +bias, q-scale; scatter Q,K,Vt into wave LDS ----
        #pragma unroll
        for (int ct = 0; ct < 6; ct++) {
            int part = ct >> 1, sub = ct & 1;
            int d = sub * 16 + lrow;
            float bias = qkv_b[part * CDIM + h * 32 + d];
            #pragma unroll
            for (int rt = 0; rt < 4; rt++)
                #pragma unroll
                for (int r = 0; r < 4; r++) {
                    int token = rt * 16 + lhi * 4 + r;
                    float v = acc[rt][ct][r] + bias;
                    if (part == 0)
                        *(short*)(qs + (token * 40 + d) * 2) = f2bf(v * SCALE_Q);
                    else if (part == 1)
                        *(short*)(kst + (token * 40 + d) * 2) = f2bf(v);
                    else
                        *(short*)(vt + (d * 72 + token) * 2) = f2bf(v);
                }
        }
        // ---- S = Q K^T ----
        bf16x8 qf[4], kf[4];
        #pragma unroll
        for (int t = 0; t < 4; t++) {
            qf[t] = *(const bf16x8*)(qs + ((t * 16 + lrow) * 40 + lhi * 8) * 2);
            kf[t] = *(const bf16x8*)(kst + ((t * 16 + lrow) * 40 + lhi * 8) * 2);
        }
        f32x4 s[4][4];
        __builtin_amdgcn_s_setprio(1);
        #pragma unroll
        for (int i = 0; i < 4; i++)
            #pragma unroll
            for (int j = 0; j < 4; j++)
                s[i][j] = __builtin_amdgcn_mfma_f32_16x16x32_bf16(qf[i], kf[j], zero, 0, 0, 0);
        __builtin_amdgcn_s_setprio(0);
        // ---- softmax rows (16-lane groups), bias + shift mask ----
        float rcpv[4][4];
        #pragma unroll
        for (int ti = 0; ti < 4; ti++) {
            #pragma unroll
            for (int r = 0; r < 4; r++) {
                int i = ti * 16 + lhi * 4 + r;
                int regi = regi_[ti][r];
                const float* bi = biasmat + h * 4096 + i * 64 + lrow;
                float sv[4]; float mx = -1e30f;
                #pragma unroll
                for (int tj = 0; tj < 4; tj++) {
                    float v = s[ti][tj][r] + bi[tj * 16];
                    v += (regj[tj] != regi) ? -100.0f : 0.0f;
                    sv[tj] = v; mx = fmaxf(mx, v);
                }
                mx = fmaxf(mx, __shfl_xor(mx, 1));
                mx = fmaxf(mx, __shfl_xor(mx, 2));
                mx = fmaxf(mx, __shfl_xor(mx, 4));
                mx = fmaxf(mx, __shfl_xor(mx, 8));
                float sum = 0.f;
                #pragma unroll
                for (int tj = 0; tj < 4; tj++) {
                    float p = __expf(sv[tj] - mx);
                    s[ti][tj][r] = p; sum += p;
                }
                sum += __shfl_xor(sum, 1);
                sum += __shfl_xor(sum, 2);
                sum += __shfl_xor(sum, 4);
                sum += __shfl_xor(sum, 8);
                rcpv[ti][r] = 1.0f / sum;
            }
        }
        // ---- P -> LDS (overlays Q/K; frags already consumed) ----
        #pragma unroll
        for (int ti = 0; ti < 4; ti++)
            #pragma unroll
            for (int tj = 0; tj < 4; tj++)
                #pragma unroll
                for (int r = 0; r < 4; r++)
                    *(short*)(pb + ((ti * 16 + lhi * 4 + r) * 72 + tj * 16 + lrow) * 2) = f2bf(s[ti][tj][r]);
        // ---- PV: out(64x32) = P(64x64) @ V(64x32) ----
        f32x4 o[4][2];
        #pragma unroll
        for (int i = 0; i < 4; i++) { o[i][0] = zero; o[i][1] = zero; }
        #pragma unroll
        for (int kk = 0; kk < 2; kk++) {
            bf16x8 vf0 = *(const bf16x8*)(vt + (lrow * 72 + kk * 32 + lhi * 8) * 2);
            bf16x8 vf1 = *(const bf16x8*)(vt + ((16 + lrow) * 72 + kk * 32 + lhi * 8) * 2);
            __builtin_amdgcn_s_setprio(1);
            #pragma unroll
            for (int ti = 0; ti < 4; ti++) {
                bf16x8 pf = *(const bf16x8*)(pb + ((ti * 16 + lrow) * 72 + kk * 32 + lhi * 8) * 2);
                o[ti][0] = __builtin_amdgcn_mfma_f32_16x16x32_bf16(pf, vf0, o[ti][0], 0, 0, 0);
                o[ti][1] = __builtin_amdgcn_mfma_f32_16x16x32_bf16(pf, vf1, o[ti][1], 0, 0, 0);
            }
            __builtin_amdgcn_s_setprio(0);
        }
        // ---- normalize, transpose via obuf, coalesced b128 store ----
        #pragma unroll
        for (int ti = 0; ti < 4; ti++)
            #pragma unroll
            for (int tj = 0; tj < 2; tj++)
                #pragma unroll
                for (int r = 0; r < 4; r++) {
                    int token = ti * 16 + lhi * 4 + r;
                    *(short*)(ob + (token * 36 + tj * 16 + lrow) * 2) =
                        f2bf(o[ti][tj][r] * rcpv[ti][r]);
                }
        short* arow = attno + (size_t)(w * 64 + lane) * CDIM + h * 32;
        #pragma unroll
        for (int c8 = 0; c8 < 4; c8++) {
            bf16x8 v = *(const bf16x8*)(ob + (lane * 36 + c8 * 8) * 2);
            *(bf16x8*)(arow + c8 * 8) = v;
        }
    }
}

// ---------------- GEMM2: out = attno @ proj_w^T + b, window-reverse --------
__global__ __launch_bounds__(256) void gemm_proj(
    const short* __restrict__ a, const short* __restrict__ wt,
    const float* __restrict__ proj_b, float* __restrict__ out)
{
    __shared__ alignas(16) short As[4096];
    __shared__ alignas(16) short Bs[4096];
    int tid = threadIdx.x;
    int hw = blockIdx.x;                       // 3072 blocks, %8==0
    int lb = (hw & 7) * 384 + (hw >> 3);
    int bm = lb / 3, bn = lb - bm * 3;
    int m0 = bm * 128, n0 = bn * 128;

    int lane = tid & 63, wv = tid >> 6;
    int c0 = wv * 128 + lane, c1 = c0 + 64;
    int l0 = invswz(c0), l1 = invswz(c1);
    const short* Ag0 = a + (size_t)(m0 + (l0 >> 2)) * CDIM + (l0 & 3) * 8;
    const short* Ag1 = a + (size_t)(m0 + (l1 >> 2)) * CDIM + (l1 & 3) * 8;
    const short* Bg0 = wt + (size_t)(n0 + (l0 >> 2)) * CDIM + (l0 & 3) * 8;
    const short* Bg1 = wt + (size_t)(n0 + (l1 >> 2)) * CDIM + (l1 & 3) * 8;
    const short* Adst0 = (const short*)((const char*)As + wv * 2048);
    const short* Adst1 = (const short*)((const char*)As + wv * 2048 + 1024);
    const short* Bdst0 = (const short*)((const char*)Bs + wv * 2048);
    const short* Bdst1 = (const short*)((const char*)Bs + wv * 2048 + 1024);

    int wr = wv >> 1, wc = wv & 1;
    int lrow = lane & 15, lhi = lane >> 4;
    int arow = wr * 64 + lrow, brow = wc * 64 + lrow;
    const short* ard = As + ((((arow * 64 + lhi * 16)) ^ ((lrow & 7) << 4)) >> 1);
    const short* brd = Bs + ((((brow * 64 + lhi * 16)) ^ ((lrow & 7) << 4)) >> 1);

    f32x4 zero = {0.f, 0.f, 0.f, 0.f};
    f32x4 acc[4][4];
    #pragma unroll
    for (int i = 0; i < 4; i++)
        #pragma unroll
        for (int j = 0; j < 4; j++) acc[i][j] = zero;

    for (int k0 = 0; k0 < CDIM; k0 += 32) {
        gl16(Ag0 + k0, Adst0);
        gl16(Bg0 + k0, Bdst0);
        gl16(Ag1 + k0, Adst1);
        gl16(Bg1 + k0, Bdst1);
        __syncthreads();
        bf16x8 af[4], bfr[4];
        #pragma unroll
        for (int t = 0; t < 4; t++) af[t]  = *(const bf16x8*)(ard + t * 512);
        #pragma unroll
        for (int t = 0; t < 4; t++) bfr[t] = *(const bf16x8*)(brd + t * 512);
        #pragma unroll
        for (int i = 0; i < 4; i++)
            #pragma unroll
            for (int j = 0; j < 4; j++)
                acc[i][j] = __builtin_amdgcn_mfma_f32_16x16x32_bf16(af[i], bfr[j], acc[i][j], 0, 0, 0);
        __syncthreads();
    }
    // epilogue: window reverse + unshift, fp32 out
    #pragma unroll
    for (int ti = 0; ti < 4; ti++) {
        #pragma unroll
        for (int r = 0; r < 4; r++) {
            int m = m0 + wr * 64 + ti * 16 + lhi * 4 + r;
            int b = m >> 12, wIdx = (m >> 6) & 63, tok = m & 63;
            int gh = ((wIdx >> 3) << 3) + (tok >> 3);
            int gw = (wIdx & 7) * 8 + (tok & 7);
            int ih = (gh + SHIFT_) & 63, iw = (gw + SHIFT_) & 63;
            size_t ob = ((size_t)(b << 12) + ih * 64 + iw) * CDIM;
            #pragma unroll
            for (int tj = 0; tj < 4; tj++) {
                int col = n0 + wc * 64 + tj * 16 + lrow;
                out[ob + col] = acc[ti][tj][r] + proj_b[col];
            }
        }
    }
}

extern "C" void kernel_launch(void* const* d_in, const int* in_sizes, int n_in,
                              void* d_out, int out_size, void* d_ws, size_t ws_size,
                              hipStream_t stream) {
    const float* x          = (const float*)d_in[0];
    const float* qkv_w      = (const float*)d_in[1];
    const float* qkv_b      = (const float*)d_in[2];
    const float* proj_w     = (const float*)d_in[3];
    const float* proj_b     = (const float*)d_in[4];
    const float* bias_table = (const float*)d_in[5];
    const int*   rel_index  = (const int*)d_in[6];
    float* out = (float*)d_out;
    char* ws = (char*)d_ws;

    short* qkvwt   = (short*)(ws);                 //  884736 B
    short* projwt  = (short*)(ws + 884736);        //  294912 B
    float* biasmat = (float*)(ws + 1179648);       //  786432 B
    short* attno   = (short*)(ws + 1966080);       //  100663296 B -> ~102.6 MB

    prep_kernel<<<1728, 256, 0, stream>>>(qkv_w, proj_w, bias_table, rel_index,
                                          qkvwt, projwt, biasmat);
    fused_qa<<<2048, 256, 0, stream>>>(x, qkvwt, qkv_b, biasmat, attno);
    gemm_proj<<<3072, 256, 0, stream>>>(attno, projwt, proj_b, out);
}

// Round 5
// 1098.870 us; speedup vs baseline: 1.3802x; 1.3802x over previous
//
#include <hip/hip_runtime.h>
#include <hip/hip_bf16.h>

#define CDIM 384
#define NQKV 1152
#define HEADS 12
#define SHIFT_ 4
#define SCALE_Q 0.17677669529663687f  // 32^-0.5

typedef __attribute__((ext_vector_type(8))) short bf16x8;
typedef __attribute__((ext_vector_type(4))) float f32x4;
typedef __attribute__((ext_vector_type(4))) float float4_t;

__device__ inline short f2bf(float f) {
    union { float f; unsigned u; } v; v.f = f;
    unsigned r = v.u + 0x7FFFu + ((v.u >> 16) & 1u);
    return (short)(r >> 16);
}

__device__ inline void gl16(const short* g, const short* l) {
    __builtin_amdgcn_global_load_lds((const __attribute__((address_space(1))) void*)g,
                                     (__attribute__((address_space(3))) void*)l, 16, 0, 0);
}

// inverse of the LDS chunk swizzle (16B chunks, rows of 4 chunks)
__device__ inline int invswz(int c) {
    int b2 = (c >> 2) & 1, b3 = (c >> 3) & 1, b4 = (c >> 4) & 1;
    return (c & ~7) | ((b2 ^ b4) << 2) | (((((c >> 1) & 1)) ^ b3) << 1) | ((c & 1) ^ b2 ^ b4);
}

// ---------------- prep: weight transpose->bf16, bias matrix ----------------
__global__ void prep_kernel(const float* __restrict__ qkv_w,
                            const float* __restrict__ proj_w,
                            const float* __restrict__ bias_table,
                            const int* __restrict__ rel_index,
                            short* __restrict__ qkvwt,
                            short* __restrict__ projwt,
                            float* __restrict__ biasmat) {
    int t = blockIdx.x * 256 + threadIdx.x;
    if (t < NQKV * CDIM) {             // qkvwt[n][k] = qkv_w[k][n]
        int n = t / CDIM, k = t - n * CDIM;
        qkvwt[t] = f2bf(qkv_w[k * NQKV + n]);
    }
    if (t < CDIM * CDIM) {             // projwt[n][k] = proj_w[k][n]
        int n = t / CDIM, k = t - n * CDIM;
        projwt[t] = f2bf(proj_w[k * CDIM + n]);
    }
    if (t < HEADS * 64 * 64) {         // biasmat[h][i][j]
        int h = t >> 12, ij = t & 4095;
        biasmat[t] = bias_table[rel_index[ij] * HEADS + h];
    }
}

// ---------------- fused qkv + attention: one block per window --------------
// 4 waves, wave = 3 heads. x staged cooperatively in K-slices of 64 into a
// shared 16 KB swizzled bf16 buffer (prefetch 1 slice ahead). Per-wave
// attention scratch wave-private. LDS 16384 + 4*14848 + 256 = 76032 B ->
// 2 blocks/CU (2 waves/SIMD).
__global__ __launch_bounds__(256, 2) void fused_qa(
    const float* __restrict__ x, const short* __restrict__ qkvwt,
    const float* __restrict__ qkv_b, const float* __restrict__ biasmat,
    short* __restrict__ attno)
{
    __shared__ __attribute__((aligned(16))) char smem[76032];
    char* xs = smem;                   // staged x slice [64 tok][64 k] bf16, swizzled
    int tid = threadIdx.x;
    int lane = tid & 63, wv = tid >> 6;
    int lrow = lane & 15, lhi = lane >> 4;
    char* pw  = smem + 16384 + wv * 14848;
    char* qs  = pw;                    // Q, stride 40 shorts
    char* kst = pw + 5120;             // K, stride 40 shorts
    char* vt  = pw + 10240;            // Vt, stride 72 shorts
    char* pb  = pw;                    // P, stride 72 shorts (overlays Q+K)
    char* ob  = pw + 10240;            // obuf, stride 36 shorts (overlays Vt)
    int* regbuf = (int*)(smem + 75776);

    int w = blockIdx.x;
    int b = w >> 6, wIdx = w & 63;

    if (tid < 64) {                    // shift-mask region ids
        int gh = ((wIdx >> 3) << 3) + (tid >> 3);
        int gw = (wIdx & 7) * 8 + (tid & 7);
        int rh = gh < 56 ? 0 : (gh < 60 ? 1 : 2);
        int rw = gw < 56 ? 0 : (gw < 60 ? 1 : 2);
        regbuf[tid] = rh * 3 + rw;
    }
    __syncthreads();

    // staging source: thread t stages row t>>2, 16-float chunk t&3 of each slice
    int srow = tid >> 2, sq = tid & 3;
    const float* srcrow;
    {
        int gh = ((wIdx >> 3) << 3) + (srow >> 3);
        int gw = (wIdx & 7) * 8 + (srow & 7);
        int sh_ = (gh + SHIFT_) & 63, sw_ = (gw + SHIFT_) & 63;
        srcrow = x + (size_t)(b * 4096 + sh_ * 64 + sw_) * CDIM + sq * 16;
    }
    int sbase = srow * 128 + sq * 32;
    int sswz = (srow & 7) << 4;
    int aswz = (lrow & 7) << 4;

    f32x4 zero = {0.f, 0.f, 0.f, 0.f};
    int regj[4], regi_[4][4];
    #pragma unroll
    for (int tj = 0; tj < 4; tj++) regj[tj] = regbuf[tj * 16 + lrow];
    #pragma unroll
    for (int ti = 0; ti < 4; ti++)
        #pragma unroll
        for (int r = 0; r < 4; r++) regi_[ti][r] = regbuf[ti * 16 + lhi * 4 + r];

    for (int hi = 0; hi < 3; hi++) {
        int h = wv * 3 + hi;
        // ---- qkv GEMM for this head: 64 tok x (32q|32k|32v), K=384 ----
        f32x4 acc[4][6];
        #pragma unroll
        for (int i = 0; i < 4; i++)
            #pragma unroll
            for (int j = 0; j < 6; j++) acc[i][j] = zero;
        const short* brow[6];
        #pragma unroll
        for (int ct = 0; ct < 6; ct++) {
            int part = ct >> 1, sub = ct & 1;
            brow[ct] = qkvwt + (size_t)(part * CDIM + h * 32 + sub * 16 + lrow) * CDIM + lhi * 8;
        }
        // prefetch slice 0
        float4_t s0 = *(const float4_t*)(srcrow);
        float4_t s1 = *(const float4_t*)(srcrow + 4);
        float4_t s2 = *(const float4_t*)(srcrow + 8);
        float4_t s3 = *(const float4_t*)(srcrow + 12);
        for (int sl = 0; sl < 6; sl++) {
            bf16x8 w0, w1;
            #pragma unroll
            for (int i = 0; i < 4; i++) {
                w0[i] = f2bf(s0[i]); w0[4 + i] = f2bf(s1[i]);
                w1[i] = f2bf(s2[i]); w1[4 + i] = f2bf(s3[i]);
            }
            __syncthreads();           // prev slice fully consumed
            *(bf16x8*)(xs + (sbase ^ sswz)) = w0;
            *(bf16x8*)(xs + ((sbase + 16) ^ sswz)) = w1;
            __syncthreads();           // slice visible to all waves
            if (sl < 5) {              // issue next-slice loads early (T14)
                const float* p = srcrow + (sl + 1) * 64;
                s0 = *(const float4_t*)(p);
                s1 = *(const float4_t*)(p + 4);
                s2 = *(const float4_t*)(p + 8);
                s3 = *(const float4_t*)(p + 12);
            }
            #pragma unroll
            for (int ksub = 0; ksub < 2; ksub++) {
                int ks = sl * 2 + ksub;
                bf16x8 bfr[6];
                #pragma unroll
                for (int ct = 0; ct < 6; ct++) bfr[ct] = *(const bf16x8*)(brow[ct] + ks * 32);
                bf16x8 af[4];
                #pragma unroll
                for (int rt = 0; rt < 4; rt++)
                    af[rt] = *(const bf16x8*)(xs + ((((rt * 16 + lrow) << 7) + ksub * 64 + lhi * 16) ^ aswz));
                __builtin_amdgcn_s_setprio(1);
                #pragma unroll
                for (int rt = 0; rt < 4; rt++)
                    #pragma unroll
                    for (int ct = 0; ct < 6; ct++)
                        acc[rt][ct] = __builtin_amdgcn_mfma_f32_16x16x32_bf16(af[rt], bfr[ct], acc[rt][ct], 0, 0, 0);
                __builtin_amdgcn_s_setprio(0);
            }
        }
        // ---- epilogue: +bias, q-scale; scatter Q,K,Vt into wave LDS ----
        #pragma unroll
        for (int ct = 0; ct < 6; ct++) {
            int part = ct >> 1, sub = ct & 1;
            int d = sub * 16 + lrow;
            float bias = qkv_b[part * CDIM + h * 32 + d];
            #pragma unroll
            for (int rt = 0; rt < 4; rt++)
                #pragma unroll
                for (int r = 0; r < 4; r++) {
                    int token = rt * 16 + lhi * 4 + r;
                    float v = acc[rt][ct][r] + bias;
                    if (part == 0)
                        *(short*)(qs + (token * 40 + d) * 2) = f2bf(v * SCALE_Q);
                    else if (part == 1)
                        *(short*)(kst + (token * 40 + d) * 2) = f2bf(v);
                    else
                        *(short*)(vt + (d * 72 + token) * 2) = f2bf(v);
                }
        }
        // ---- S = Q K^T ----
        bf16x8 qf[4], kf[4];
        #pragma unroll
        for (int t = 0; t < 4; t++) {
            qf[t] = *(const bf16x8*)(qs + ((t * 16 + lrow) * 40 + lhi * 8) * 2);
            kf[t] = *(const bf16x8*)(kst + ((t * 16 + lrow) * 40 + lhi * 8) * 2);
        }
        f32x4 s[4][4];
        __builtin_amdgcn_s_setprio(1);
        #pragma unroll
        for (int i = 0; i < 4; i++)
            #pragma unroll
            for (int j = 0; j < 4; j++)
                s[i][j] = __builtin_amdgcn_mfma_f32_16x16x32_bf16(qf[i], kf[j], zero, 0, 0, 0);
        __builtin_amdgcn_s_setprio(0);
        // ---- softmax rows (16-lane groups), bias + shift mask ----
        float rcpv[4][4];
        #pragma unroll
        for (int ti = 0; ti < 4; ti++) {
            #pragma unroll
            for (int r = 0; r < 4; r++) {
                int i = ti * 16 + lhi * 4 + r;
                int regi = regi_[ti][r];
                const float* bi = biasmat + h * 4096 + i * 64 + lrow;
                float sv[4]; float mx = -1e30f;
                #pragma unroll
                for (int tj = 0; tj < 4; tj++) {
                    float v = s[ti][tj][r] + bi[tj * 16];
                    v += (regj[tj] != regi) ? -100.0f : 0.0f;
                    sv[tj] = v; mx = fmaxf(mx, v);
                }
                mx = fmaxf(mx, __shfl_xor(mx, 1));
                mx = fmaxf(mx, __shfl_xor(mx, 2));
                mx = fmaxf(mx, __shfl_xor(mx, 4));
                mx = fmaxf(mx, __shfl_xor(mx, 8));
                float sum = 0.f;
                #pragma unroll
                for (int tj = 0; tj < 4; tj++) {
                    float p = __expf(sv[tj] - mx);
                    s[ti][tj][r] = p; sum += p;
                }
                sum += __shfl_xor(sum, 1);
                sum += __shfl_xor(sum, 2);
                sum += __shfl_xor(sum, 4);
                sum += __shfl_xor(sum, 8);
                rcpv[ti][r] = 1.0f / sum;
            }
        }
        // ---- P -> LDS (overlays Q/K; frags already consumed) ----
        #pragma unroll
        for (int ti = 0; ti < 4; ti++)
            #pragma unroll
            for (int tj = 0; tj < 4; tj++)
                #pragma unroll
                for (int r = 0; r < 4; r++)
                    *(short*)(pb + ((ti * 16 + lhi * 4 + r) * 72 + tj * 16 + lrow) * 2) = f2bf(s[ti][tj][r]);
        // ---- PV: out(64x32) = P(64x64) @ V(64x32) ----
        f32x4 o[4][2];
        #pragma unroll
        for (int i = 0; i < 4; i++) { o[i][0] = zero; o[i][1] = zero; }
        #pragma unroll
        for (int kk = 0; kk < 2; kk++) {
            bf16x8 vf0 = *(const bf16x8*)(vt + (lrow * 72 + kk * 32 + lhi * 8) * 2);
            bf16x8 vf1 = *(const bf16x8*)(vt + ((16 + lrow) * 72 + kk * 32 + lhi * 8) * 2);
            __builtin_amdgcn_s_setprio(1);
            #pragma unroll
            for (int ti = 0; ti < 4; ti++) {
                bf16x8 pf = *(const bf16x8*)(pb + ((ti * 16 + lrow) * 72 + kk * 32 + lhi * 8) * 2);
                o[ti][0] = __builtin_amdgcn_mfma_f32_16x16x32_bf16(pf, vf0, o[ti][0], 0, 0, 0);
                o[ti][1] = __builtin_amdgcn_mfma_f32_16x16x32_bf16(pf, vf1, o[ti][1], 0, 0, 0);
            }
            __builtin_amdgcn_s_setprio(0);
        }
        // ---- normalize, transpose via obuf, coalesced b128 store ----
        #pragma unroll
        for (int ti = 0; ti < 4; ti++)
            #pragma unroll
            for (int tj = 0; tj < 2; tj++)
                #pragma unroll
                for (int r = 0; r < 4; r++) {
                    int token = ti * 16 + lhi * 4 + r;
                    *(short*)(ob + (token * 36 + tj * 16 + lrow) * 2) =
                        f2bf(o[ti][tj][r] * rcpv[ti][r]);
                }
        short* arow = attno + (size_t)(w * 64 + lane) * CDIM + h * 32;
        #pragma unroll
        for (int c8 = 0; c8 < 4; c8++) {
            bf16x8 v = *(const bf16x8*)(ob + (lane * 36 + c8 * 8) * 2);
            *(bf16x8*)(arow + c8 * 8) = v;
        }
    }
}

// ---------------- GEMM2: out = attno @ proj_w^T + b, window-reverse --------
__global__ __launch_bounds__(256) void gemm_proj(
    const short* __restrict__ a, const short* __restrict__ wt,
    const float* __restrict__ proj_b, float* __restrict__ out)
{
    __shared__ alignas(16) short As[4096];
    __shared__ alignas(16) short Bs[4096];
    int tid = threadIdx.x;
    int hw = blockIdx.x;                       // 3072 blocks, %8==0
    int lb = (hw & 7) * 384 + (hw >> 3);
    int bm = lb / 3, bn = lb - bm * 3;
    int m0 = bm * 128, n0 = bn * 128;

    int lane = tid & 63, wv = tid >> 6;
    int c0 = wv * 128 + lane, c1 = c0 + 64;
    int l0 = invswz(c0), l1 = invswz(c1);
    const short* Ag0 = a + (size_t)(m0 + (l0 >> 2)) * CDIM + (l0 & 3) * 8;
    const short* Ag1 = a + (size_t)(m0 + (l1 >> 2)) * CDIM + (l1 & 3) * 8;
    const short* Bg0 = wt + (size_t)(n0 + (l0 >> 2)) * CDIM + (l0 & 3) * 8;
    const short* Bg1 = wt + (size_t)(n0 + (l1 >> 2)) * CDIM + (l1 & 3) * 8;
    const short* Adst0 = (const short*)((const char*)As + wv * 2048);
    const short* Adst1 = (const short*)((const char*)As + wv * 2048 + 1024);
    const short* Bdst0 = (const short*)((const char*)Bs + wv * 2048);
    const short* Bdst1 = (const short*)((const char*)Bs + wv * 2048 + 1024);

    int wr = wv >> 1, wc = wv & 1;
    int lrow = lane & 15, lhi = lane >> 4;
    int arow = wr * 64 + lrow, brow = wc * 64 + lrow;
    const short* ard = As + ((((arow * 64 + lhi * 16)) ^ ((lrow & 7) << 4)) >> 1);
    const short* brd = Bs + ((((brow * 64 + lhi * 16)) ^ ((lrow & 7) << 4)) >> 1);

    f32x4 zero = {0.f, 0.f, 0.f, 0.f};
    f32x4 acc[4][4];
    #pragma unroll
    for (int i = 0; i < 4; i++)
        #pragma unroll
        for (int j = 0; j < 4; j++) acc[i][j] = zero;

    for (int k0 = 0; k0 < CDIM; k0 += 32) {
        gl16(Ag0 + k0, Adst0);
        gl16(Bg0 + k0, Bdst0);
        gl16(Ag1 + k0, Adst1);
        gl16(Bg1 + k0, Bdst1);
        __syncthreads();
        bf16x8 af[4], bfr[4];
        #pragma unroll
        for (int t = 0; t < 4; t++) af[t]  = *(const bf16x8*)(ard + t * 512);
        #pragma unroll
        for (int t = 0; t < 4; t++) bfr[t] = *(const bf16x8*)(brd + t * 512);
        #pragma unroll
        for (int i = 0; i < 4; i++)
            #pragma unroll
            for (int j = 0; j < 4; j++)
                acc[i][j] = __builtin_amdgcn_mfma_f32_16x16x32_bf16(af[i], bfr[j], acc[i][j], 0, 0, 0);
        __syncthreads();
    }
    // epilogue: window reverse + unshift, fp32 out
    #pragma unroll
    for (int ti = 0; ti < 4; ti++) {
        #pragma unroll
        for (int r = 0; r < 4; r++) {
            int m = m0 + wr * 64 + ti * 16 + lhi * 4 + r;
            int b = m >> 12, wIdx = (m >> 6) & 63, tok = m & 63;
            int gh = ((wIdx >> 3) << 3) + (tok >> 3);
            int gw = (wIdx & 7) * 8 + (tok & 7);
            int ih = (gh + SHIFT_) & 63, iw = (gw + SHIFT_) & 63;
            size_t ob = ((size_t)(b << 12) + ih * 64 + iw) * CDIM;
            #pragma unroll
            for (int tj = 0; tj < 4; tj++) {
                int col = n0 + wc * 64 + tj * 16 + lrow;
                out[ob + col] = acc[ti][tj][r] + proj_b[col];
            }
        }
    }
}

extern "C" void kernel_launch(void* const* d_in, const int* in_sizes, int n_in,
                              void* d_out, int out_size, void* d_ws, size_t ws_size,
                              hipStream_t stream) {
    const float* x          = (const float*)d_in[0];
    const float* qkv_w      = (const float*)d_in[1];
    const float* qkv_b      = (const float*)d_in[2];
    const float* proj_w     = (const float*)d_in[3];
    const float* proj_b     = (const float*)d_in[4];
    const float* bias_table = (const float*)d_in[5];
    const int*   rel_index  = (const int*)d_in[6];
    float* out = (float*)d_out;
    char* ws = (char*)d_ws;

    short* qkvwt   = (short*)(ws);                 //  884736 B
    short* projwt  = (short*)(ws + 884736);        //  294912 B
    float* biasmat = (float*)(ws + 1179648);       //  786432 B
    short* attno   = (short*)(ws + 1966080);       //  100663296 B -> ~102.6 MB

    prep_kernel<<<1728, 256, 0, stream>>>(qkv_w, proj_w, bias_table, rel_index,
                                          qkvwt, projwt, biasmat);
    fused_qa<<<2048, 256, 0, stream>>>(x, qkvwt, qkv_b, biasmat, attno);
    gemm_proj<<<3072, 256, 0, stream>>>(attno, projwt, proj_b, out);
}

// Round 6
// 593.309 us; speedup vs baseline: 2.5564x; 1.8521x over previous
//
#include <hip/hip_runtime.h>
#include <hip/hip_bf16.h>

#define CDIM 384
#define NQKV 1152
#define HEADS 12
#define SHIFT_ 4
#define SCALE_Q 0.17677669529663687f  // 32^-0.5

typedef __attribute__((ext_vector_type(8))) short bf16x8;
typedef __attribute__((ext_vector_type(4))) float f32x4;
typedef __attribute__((ext_vector_type(4))) float float4_t;
typedef __attribute__((ext_vector_type(4))) unsigned u32x4;

__device__ inline short f2bf(float f) {
    union { float f; unsigned u; } v; v.f = f;
    unsigned r = v.u + 0x7FFFu + ((v.u >> 16) & 1u);
    return (short)(r >> 16);
}

__device__ inline unsigned cvtpk(float lo, float hi) {
    unsigned r;
    asm volatile("v_cvt_pk_bf16_f32 %0, %1, %2" : "=v"(r) : "v"(lo), "v"(hi));
    return r;
}

__device__ inline bf16x8 mk8(unsigned w0, unsigned w1, unsigned w2, unsigned w3) {
    u32x4 t = {w0, w1, w2, w3};
    return __builtin_bit_cast(bf16x8, t);
}

// Regroup: given two acc tiles (rows 0-15 in accA, 16-31 in accB; per-lane
// col=lane&15, rows lhi*4+r) packed as bf16 pairs p0..p3, build the MFMA
// operand fragment (per-lane col=lane&15, rows lhi*8..lhi*8+7).
__device__ inline bf16x8 regroup(unsigned p0, unsigned p1, unsigned p2,
                                 unsigned p3, int lane) {
    int lhi = (lane >> 4) & 3;
    int s0 = (lane & 15) + ((lhi & 1) ? 32 : 0);
    int s1 = s0 + 16;
    unsigned a0 = __shfl(p0, s0), b0 = __shfl(p2, s0);
    unsigned a1 = __shfl(p1, s0), b1 = __shfl(p3, s0);
    unsigned a2 = __shfl(p0, s1), b2 = __shfl(p2, s1);
    unsigned a3 = __shfl(p1, s1), b3 = __shfl(p3, s1);
    bool hi = lhi >= 2;
    return mk8(hi ? b0 : a0, hi ? b1 : a1, hi ? b2 : a2, hi ? b3 : a3);
}

__device__ inline void gl16(const short* g, const short* l) {
    __builtin_amdgcn_global_load_lds((const __attribute__((address_space(1))) void*)g,
                                     (__attribute__((address_space(3))) void*)l, 16, 0, 0);
}

__device__ inline int invswz(int c) {
    int b2 = (c >> 2) & 1, b3 = (c >> 3) & 1, b4 = (c >> 4) & 1;
    return (c & ~7) | ((b2 ^ b4) << 2) | (((((c >> 1) & 1)) ^ b3) << 1) | ((c & 1) ^ b2 ^ b4);
}

// ---------------- prep: weight transpose->bf16, bias matrix (transposed) ---
__global__ void prep_kernel(const float* __restrict__ qkv_w,
                            const float* __restrict__ proj_w,
                            const float* __restrict__ bias_table,
                            const int* __restrict__ rel_index,
                            short* __restrict__ qkvwt,
                            short* __restrict__ projwt,
                            float* __restrict__ biasT) {
    int t = blockIdx.x * 256 + threadIdx.x;
    if (t < NQKV * CDIM) {             // qkvwt[n][k] = qkv_w[k][n]
        int n = t / CDIM, k = t - n * CDIM;
        qkvwt[t] = f2bf(qkv_w[k * NQKV + n]);
    }
    if (t < CDIM * CDIM) {             // projwt[n][k] = proj_w[k][n]
        int n = t / CDIM, k = t - n * CDIM;
        projwt[t] = f2bf(proj_w[k * CDIM + n]);
    }
    if (t < HEADS * 64 * 64) {         // biasT[h][key j][query i]
        int h = t >> 12, jq = t & 4095;
        int j = jq >> 6, i = jq & 63;
        biasT[t] = bias_table[rel_index[i * 64 + j] * HEADS + h];
    }
}

// ---------------- fused qkv + attention: one block per window --------------
// 4 waves, wave = 3 heads. Xs staged once (48K); Q/K/S/P entirely in
// registers via W-as-A layouts + shfl regroup; only Vt in LDS (4.6K/wave,
// obuf overlays it). LDS total 67840 B -> 2 blocks/CU (2 waves/SIMD).
__global__ __launch_bounds__(256, 2) void fused_qa(
    const float* __restrict__ x, const short* __restrict__ qkvwt,
    const float* __restrict__ qkv_b, const float* __restrict__ biasT,
    short* __restrict__ attno)
{
    __shared__ __attribute__((aligned(16))) char smem[67840];
    char* xs = smem;                           // [64][384] bf16, XOR-swizzled
    int tid = threadIdx.x;
    int lane = tid & 63, wv = tid >> 6;
    int lrow = lane & 15, lhi = lane >> 4;
    char* vt = smem + 49152 + wv * 4608;       // Vt [32][72] shorts
    char* ob = vt;                             // obuf [64][36] shorts (overlay)
    int* regbuf = (int*)(smem + 49152 + 18432);

    int hw = blockIdx.x;
    int w = (hw & 7) * 256 + (hw >> 3);        // XCD-chunked window id
    int b = w >> 6, wIdx = w & 63;
    bool needmask = ((wIdx >> 3) == 7) || ((wIdx & 7) == 7);

    if (tid < 64) {                            // shift-mask region ids
        int gh = ((wIdx >> 3) << 3) + (tid >> 3);
        int gw = (wIdx & 7) * 8 + (tid & 7);
        int rh = gh < 56 ? 0 : (gh < 60 ? 1 : 2);
        int rw = gw < 56 ? 0 : (gw < 60 ? 1 : 2);
        regbuf[tid] = rh * 3 + rw;
    }

    // ---- stage x window -> Xs (bf16, XOR-swizzled), once ----
    #pragma unroll
    for (int it = 0; it < 6; it++) {
        int c = it * 256 + tid;                // 1536 chunks of 16 floats
        int tok = c / 24, kc = (c - tok * 24) * 16;
        int gh = ((wIdx >> 3) << 3) + (tok >> 3);
        int gw = (wIdx & 7) * 8 + (tok & 7);
        int sh_ = (gh + SHIFT_) & 63, sw_ = (gw + SHIFT_) & 63;
        const float* src = x + (size_t)(b * 4096 + sh_ * 64 + sw_) * CDIM + kc;
        float4_t a0 = *(const float4_t*)(src);
        float4_t a1 = *(const float4_t*)(src + 4);
        float4_t a2 = *(const float4_t*)(src + 8);
        float4_t a3 = *(const float4_t*)(src + 12);
        bf16x8 w0, w1;
        #pragma unroll
        for (int i = 0; i < 4; i++) {
            w0[i] = f2bf(a0[i]); w0[4 + i] = f2bf(a1[i]);
            w1[i] = f2bf(a2[i]); w1[4 + i] = f2bf(a3[i]);
        }
        int base = tok * 768 + kc * 2, sw = (tok & 7) << 4;
        *(bf16x8*)(xs + (base ^ sw)) = w0;
        *(bf16x8*)(xs + ((base + 16) ^ sw)) = w1;
    }
    __syncthreads();                           // only block-wide barrier

    int aswz = (lrow & 7) << 4;
    f32x4 zero = {0.f, 0.f, 0.f, 0.f};

    int rq[4], rk[4][4];                       // region ids (query/key view)
    #pragma unroll
    for (int qt = 0; qt < 4; qt++) rq[qt] = regbuf[qt * 16 + lrow];
    #pragma unroll
    for (int kt = 0; kt < 4; kt++)
        #pragma unroll
        for (int r = 0; r < 4; r++) rk[kt][r] = regbuf[kt * 16 + lhi * 4 + r];

    for (int hi = 0; hi < 3; hi++) {
        int h = wv * 3 + hi;
        // ---- qkv GEMM: Q,K via W-as-A (acc col=token); V via X-as-A ----
        const short* wq0 = qkvwt + (size_t)(h * 32 + lrow) * CDIM + lhi * 8;
        const short* wq1 = wq0 + 16 * CDIM;
        const short* wk0 = qkvwt + (size_t)(CDIM + h * 32 + lrow) * CDIM + lhi * 8;
        const short* wk1 = wk0 + 16 * CDIM;
        const short* wv0 = qkvwt + (size_t)(2 * CDIM + h * 32 + lrow) * CDIM + lhi * 8;
        const short* wv1 = wv0 + 16 * CDIM;
        f32x4 aq[2][4], ak[2][4], av[4][2];
        #pragma unroll
        for (int i = 0; i < 4; i++) {
            aq[0][i] = zero; aq[1][i] = zero; ak[0][i] = zero; ak[1][i] = zero;
            av[i][0] = zero; av[i][1] = zero;
        }
        #pragma unroll
        for (int ks = 0; ks < 12; ks++) {
            bf16x8 fq0 = *(const bf16x8*)(wq0 + ks * 32);
            bf16x8 fq1 = *(const bf16x8*)(wq1 + ks * 32);
            bf16x8 fk0 = *(const bf16x8*)(wk0 + ks * 32);
            bf16x8 fk1 = *(const bf16x8*)(wk1 + ks * 32);
            bf16x8 fv0 = *(const bf16x8*)(wv0 + ks * 32);
            bf16x8 fv1 = *(const bf16x8*)(wv1 + ks * 32);
            bf16x8 xf[4];
            #pragma unroll
            for (int tt = 0; tt < 4; tt++)
                xf[tt] = *(const bf16x8*)(xs + (((tt * 16 + lrow) * 768 + ks * 64 + lhi * 16) ^ aswz));
            __builtin_amdgcn_s_setprio(1);
            #pragma unroll
            for (int tt = 0; tt < 4; tt++) {
                aq[0][tt] = __builtin_amdgcn_mfma_f32_16x16x32_bf16(fq0, xf[tt], aq[0][tt], 0, 0, 0);
                aq[1][tt] = __builtin_amdgcn_mfma_f32_16x16x32_bf16(fq1, xf[tt], aq[1][tt], 0, 0, 0);
                ak[0][tt] = __builtin_amdgcn_mfma_f32_16x16x32_bf16(fk0, xf[tt], ak[0][tt], 0, 0, 0);
                ak[1][tt] = __builtin_amdgcn_mfma_f32_16x16x32_bf16(fk1, xf[tt], ak[1][tt], 0, 0, 0);
                av[tt][0] = __builtin_amdgcn_mfma_f32_16x16x32_bf16(xf[tt], fv0, av[tt][0], 0, 0, 0);
                av[tt][1] = __builtin_amdgcn_mfma_f32_16x16x32_bf16(xf[tt], fv1, av[tt][1], 0, 0, 0);
            }
            __builtin_amdgcn_s_setprio(0);
        }
        // ---- V epilogue -> Vt LDS (acc: col=dim, row=token) ----
        float bv0 = qkv_b[2 * CDIM + h * 32 + lrow];
        float bv1 = qkv_b[2 * CDIM + h * 32 + 16 + lrow];
        #pragma unroll
        for (int tt = 0; tt < 4; tt++)
            #pragma unroll
            for (int r = 0; r < 4; r++) {
                int token = tt * 16 + lhi * 4 + r;
                *(short*)(vt + (lrow * 72 + token) * 2)        = f2bf(av[tt][0][r] + bv0);
                *(short*)(vt + ((16 + lrow) * 72 + token) * 2) = f2bf(av[tt][1][r] + bv1);
            }
        // ---- Q/K epilogue -> fragments (bias, scale, pack, regroup) ----
        float bq[2][4], bk[2][4];
        #pragma unroll
        for (int dt = 0; dt < 2; dt++)
            #pragma unroll
            for (int r = 0; r < 4; r++) {
                bq[dt][r] = qkv_b[h * 32 + dt * 16 + lhi * 4 + r];
                bk[dt][r] = qkv_b[CDIM + h * 32 + dt * 16 + lhi * 4 + r];
            }
        bf16x8 qf[4], kf[4];
        #pragma unroll
        for (int tt = 0; tt < 4; tt++) {
            unsigned p0 = cvtpk((aq[0][tt][0] + bq[0][0]) * SCALE_Q, (aq[0][tt][1] + bq[0][1]) * SCALE_Q);
            unsigned p1 = cvtpk((aq[0][tt][2] + bq[0][2]) * SCALE_Q, (aq[0][tt][3] + bq[0][3]) * SCALE_Q);
            unsigned p2 = cvtpk((aq[1][tt][0] + bq[1][0]) * SCALE_Q, (aq[1][tt][1] + bq[1][1]) * SCALE_Q);
            unsigned p3 = cvtpk((aq[1][tt][2] + bq[1][2]) * SCALE_Q, (aq[1][tt][3] + bq[1][3]) * SCALE_Q);
            qf[tt] = regroup(p0, p1, p2, p3, lane);
            p0 = cvtpk(ak[0][tt][0] + bk[0][0], ak[0][tt][1] + bk[0][1]);
            p1 = cvtpk(ak[0][tt][2] + bk[0][2], ak[0][tt][3] + bk[0][3]);
            p2 = cvtpk(ak[1][tt][0] + bk[1][0], ak[1][tt][1] + bk[1][1]);
            p3 = cvtpk(ak[1][tt][2] + bk[1][2], ak[1][tt][3] + bk[1][3]);
            kf[tt] = regroup(p0, p1, p2, p3, lane);
        }
        // ---- S^T = K Q^T : rows=keys(lhi*4+r), cols=queries(lane&15) ----
        f32x4 st[4][4];
        __builtin_amdgcn_s_setprio(1);
        #pragma unroll
        for (int kt = 0; kt < 4; kt++)
            #pragma unroll
            for (int qt = 0; qt < 4; qt++)
                st[kt][qt] = __builtin_amdgcn_mfma_f32_16x16x32_bf16(kf[kt], qf[qt], zero, 0, 0, 0);
        __builtin_amdgcn_s_setprio(0);
        // ---- softmax per query (lane-local row) + P fragments ----
        const float* bT = biasT + h * 4096 + lrow;  // + key*64 + qt*16
        bf16x8 pa[4][2];
        #pragma unroll
        for (int qt = 0; qt < 4; qt++) {
            float pv[16]; float sum = 0.f;
            #pragma unroll
            for (int kt = 0; kt < 4; kt++)
                #pragma unroll
                for (int r = 0; r < 4; r++) {
                    float v = st[kt][qt][r] + bT[(kt * 16 + lhi * 4 + r) * 64 + qt * 16];
                    float p = __expf(v);
                    p = (needmask && (rq[qt] != rk[kt][r])) ? 0.f : p;
                    pv[kt * 4 + r] = p; sum += p;
                }
            sum += __shfl_xor(sum, 16);
            sum += __shfl_xor(sum, 32);
            float rcp = 1.0f / sum;
            unsigned a0 = cvtpk(pv[0] * rcp, pv[1] * rcp);
            unsigned a1 = cvtpk(pv[2] * rcp, pv[3] * rcp);
            unsigned a2 = cvtpk(pv[4] * rcp, pv[5] * rcp);
            unsigned a3 = cvtpk(pv[6] * rcp, pv[7] * rcp);
            pa[qt][0] = regroup(a0, a1, a2, a3, lane);
            a0 = cvtpk(pv[8] * rcp,  pv[9] * rcp);
            a1 = cvtpk(pv[10] * rcp, pv[11] * rcp);
            a2 = cvtpk(pv[12] * rcp, pv[13] * rcp);
            a3 = cvtpk(pv[14] * rcp, pv[15] * rcp);
            pa[qt][1] = regroup(a0, a1, a2, a3, lane);
        }
        // ---- PV: out[query][dim] ----
        f32x4 ao[4][2];
        #pragma unroll
        for (int qt = 0; qt < 4; qt++) { ao[qt][0] = zero; ao[qt][1] = zero; }
        #pragma unroll
        for (int ks2 = 0; ks2 < 2; ks2++) {
            bf16x8 v0 = *(const bf16x8*)(vt + (lrow * 72 + ks2 * 32 + lhi * 8) * 2);
            bf16x8 v1 = *(const bf16x8*)(vt + ((16 + lrow) * 72 + ks2 * 32 + lhi * 8) * 2);
            __builtin_amdgcn_s_setprio(1);
            #pragma unroll
            for (int qt = 0; qt < 4; qt++) {
                ao[qt][0] = __builtin_amdgcn_mfma_f32_16x16x32_bf16(pa[qt][ks2], v0, ao[qt][0], 0, 0, 0);
                ao[qt][1] = __builtin_amdgcn_mfma_f32_16x16x32_bf16(pa[qt][ks2], v1, ao[qt][1], 0, 0, 0);
            }
            __builtin_amdgcn_s_setprio(0);
        }
        // ---- transpose via obuf (overlays Vt), coalesced b128 store ----
        #pragma unroll
        for (int qt = 0; qt < 4; qt++)
            #pragma unroll
            for (int dt = 0; dt < 2; dt++)
                #pragma unroll
                for (int r = 0; r < 4; r++) {
                    int token = qt * 16 + lhi * 4 + r;
                    *(short*)(ob + (token * 36 + dt * 16 + lrow) * 2) = f2bf(ao[qt][dt][r]);
                }
        short* arow = attno + (size_t)(w * 64 + lane) * CDIM + h * 32;
        #pragma unroll
        for (int c8 = 0; c8 < 4; c8++) {
            bf16x8 v = *(const bf16x8*)(ob + (lane * 36 + c8 * 8) * 2);
            *(bf16x8*)(arow + c8 * 8) = v;
        }
    }
}

// ---------------- GEMM2: out = attno @ proj_w^T + b, window-reverse --------
__global__ __launch_bounds__(256) void gemm_proj(
    const short* __restrict__ a, const short* __restrict__ wt,
    const float* __restrict__ proj_b, float* __restrict__ out)
{
    __shared__ alignas(16) short As[4096];
    __shared__ alignas(16) short Bs[4096];
    int tid = threadIdx.x;
    int hw = blockIdx.x;                       // 3072 blocks, %8==0
    int lb = (hw & 7) * 384 + (hw >> 3);
    int bm = lb / 3, bn = lb - bm * 3;
    int m0 = bm * 128, n0 = bn * 128;

    int lane = tid & 63, wv = tid >> 6;
    int c0 = wv * 128 + lane, c1 = c0 + 64;
    int l0 = invswz(c0), l1 = invswz(c1);
    const short* Ag0 = a + (size_t)(m0 + (l0 >> 2)) * CDIM + (l0 & 3) * 8;
    const short* Ag1 = a + (size_t)(m0 + (l1 >> 2)) * CDIM + (l1 & 3) * 8;
    const short* Bg0 = wt + (size_t)(n0 + (l0 >> 2)) * CDIM + (l0 & 3) * 8;
    const short* Bg1 = wt + (size_t)(n0 + (l1 >> 2)) * CDIM + (l1 & 3) * 8;
    const short* Adst0 = (const short*)((const char*)As + wv * 2048);
    const short* Adst1 = (const short*)((const char*)As + wv * 2048 + 1024);
    const short* Bdst0 = (const short*)((const char*)Bs + wv * 2048);
    const short* Bdst1 = (const short*)((const char*)Bs + wv * 2048 + 1024);

    int wr = wv >> 1, wc = wv & 1;
    int lrow = lane & 15, lhi = lane >> 4;
    int arow = wr * 64 + lrow, brow = wc * 64 + lrow;
    const short* ard = As + ((((arow * 64 + lhi * 16)) ^ ((lrow & 7) << 4)) >> 1);
    const short* brd = Bs + ((((brow * 64 + lhi * 16)) ^ ((lrow & 7) << 4)) >> 1);

    f32x4 zero = {0.f, 0.f, 0.f, 0.f};
    f32x4 acc[4][4];
    #pragma unroll
    for (int i = 0; i < 4; i++)
        #pragma unroll
        for (int j = 0; j < 4; j++) acc[i][j] = zero;

    for (int k0 = 0; k0 < CDIM; k0 += 32) {
        gl16(Ag0 + k0, Adst0);
        gl16(Bg0 + k0, Bdst0);
        gl16(Ag1 + k0, Adst1);
        gl16(Bg1 + k0, Bdst1);
        __syncthreads();
        bf16x8 af[4], bfr[4];
        #pragma unroll
        for (int t = 0; t < 4; t++) af[t]  = *(const bf16x8*)(ard + t * 512);
        #pragma unroll
        for (int t = 0; t < 4; t++) bfr[t] = *(const bf16x8*)(brd + t * 512);
        #pragma unroll
        for (int i = 0; i < 4; i++)
            #pragma unroll
            for (int j = 0; j < 4; j++)
                acc[i][j] = __builtin_amdgcn_mfma_f32_16x16x32_bf16(af[i], bfr[j], acc[i][j], 0, 0, 0);
        __syncthreads();
    }
    // epilogue: window reverse + unshift, fp32 out
    #pragma unroll
    for (int ti = 0; ti < 4; ti++) {
        #pragma unroll
        for (int r = 0; r < 4; r++) {
            int m = m0 + wr * 64 + ti * 16 + lhi * 4 + r;
            int b = m >> 12, wIdx = (m >> 6) & 63, tok = m & 63;
            int gh = ((wIdx >> 3) << 3) + (tok >> 3);
            int gw = (wIdx & 7) * 8 + (tok & 7);
            int ih = (gh + SHIFT_) & 63, iw = (gw + SHIFT_) & 63;
            size_t ob = ((size_t)(b << 12) + ih * 64 + iw) * CDIM;
            #pragma unroll
            for (int tj = 0; tj < 4; tj++) {
                int col = n0 + wc * 64 + tj * 16 + lrow;
                out[ob + col] = acc[ti][tj][r] + proj_b[col];
            }
        }
    }
}

extern "C" void kernel_launch(void* const* d_in, const int* in_sizes, int n_in,
                              void* d_out, int out_size, void* d_ws, size_t ws_size,
                              hipStream_t stream) {
    const float* x          = (const float*)d_in[0];
    const float* qkv_w      = (const float*)d_in[1];
    const float* qkv_b      = (const float*)d_in[2];
    const float* proj_w     = (const float*)d_in[3];
    const float* proj_b     = (const float*)d_in[4];
    const float* bias_table = (const float*)d_in[5];
    const int*   rel_index  = (const int*)d_in[6];
    float* out = (float*)d_out;
    char* ws = (char*)d_ws;

    short* qkvwt   = (short*)(ws);                 //  884736 B
    short* projwt  = (short*)(ws + 884736);        //  294912 B
    float* biasT   = (float*)(ws + 1179648);       //  196608 B
    short* attno   = (short*)(ws + 1376256);       //  100663296 B -> ~102 MB

    prep_kernel<<<1728, 256, 0, stream>>>(qkv_w, proj_w, bias_table, rel_index,
                                          qkvwt, projwt, biasT);
    fused_qa<<<2048, 256, 0, stream>>>(x, qkvwt, qkv_b, biasT, attno);
    gemm_proj<<<3072, 256, 0, stream>>>(attno, projwt, proj_b, out);
}